// Round 5
// baseline (269.016 us; speedup 1.0000x reference)
//
#include <hip/hip_runtime.h>
#include <hip/hip_bf16.h>

typedef unsigned int u32;
typedef __bf16 bf16x8 __attribute__((ext_vector_type(8)));
typedef float  f32x4  __attribute__((ext_vector_type(4)));

#define NTOK 8192
#define DIM  512
#define FDIM 2048
#define NEXP 8
#define NRB_MAX 40                     // max 256-row blocks after per-expert padding
#define NPAD (NRB_MAX * 256)           // 10240 padded rows

// ---- workspace layout (bytes) ----
// WT region shared: W1t before GEMM1, overwritten by W2t after GEMM1.
#define OFF_WT    0ull                 // bf16 16,777,216 B
#define OFF_XG    16777216ull          // bf16 [NPAD][DIM]   10,485,760 B
#define OFF_H     27262976ull          // bf16 [NPAD][FDIM]  41,943,040 B
#define OFF_SCALE 69206016ull          // f32  [NTOK]            32,768 B
#define OFF_CNT   69238784ull          // int  [E]
#define OFF_RBEXP 69238912ull          // int  [NRB_MAX]
#define OFF_LIST  69239168ull          // int  [E][NTOK]        262,144 B
#define OFF_GLIST 69501312ull          // int  [NPAD]            40,960 B

__device__ __forceinline__ u32 rotl32(u32 x, int r) { return (x << r) | (x >> (32 - r)); }

__device__ __forceinline__ void threefry2x32(u32 k0, u32 k1, u32 x0, u32 x1,
                                             u32& y0, u32& y1) {
  u32 ks2 = k0 ^ k1 ^ 0x1BD11BDAu;
  x0 += k0; x1 += k1;
#define TF_RND(r) { x0 += x1; x1 = rotl32(x1, r); x1 ^= x0; }
  TF_RND(13) TF_RND(15) TF_RND(26) TF_RND(6)
  x0 += k1;  x1 += ks2 + 1u;
  TF_RND(17) TF_RND(29) TF_RND(16) TF_RND(24)
  x0 += ks2; x1 += k0 + 2u;
  TF_RND(13) TF_RND(15) TF_RND(26) TF_RND(6)
  x0 += k0;  x1 += k1 + 3u;
  TF_RND(17) TF_RND(29) TF_RND(16) TF_RND(24)
  x0 += k1;  x1 += ks2 + 4u;
  TF_RND(13) TF_RND(15) TF_RND(26) TF_RND(6)
  x0 += ks2; x1 += k0 + 5u;
#undef TF_RND
  y0 = x0; y1 = x1;
}

__device__ __forceinline__ float jax_uniform(u32 j) {
  u32 y0, y1;
  threefry2x32(0u, 42u, 0u, j, y0, y1);
  u32 bits = y0 ^ y1;
  return __uint_as_float((bits >> 9) | 0x3F800000u) - 1.0f;
}

__device__ __forceinline__ unsigned short f2b(float f) {
  u32 u = __float_as_uint(f);
  u32 r = (u + 0x7FFFu + ((u >> 16) & 1u)) >> 16;
  return (unsigned short)r;
}

// ---------------- router ----------------
__global__ __launch_bounds__(256) void router_kernel(
    const float* __restrict__ attr, const float* __restrict__ Wr,
    const float* __restrict__ br, float* __restrict__ scale,
    int* __restrict__ cnt, int* __restrict__ list) {
  int i = blockIdx.x * 256 + threadIdx.x;
  if (i >= NTOK) return;
  float a[3];
#pragma unroll
  for (int c = 0; c < 3; ++c) {
    float u = jax_uniform((u32)(3 * i + c));
    a[c] = attr[3 * i + c] * ((1.0f + 0.01f) - 2.0f * 0.01f * u);
  }
  float logits[NEXP];
#pragma unroll
  for (int e = 0; e < NEXP; ++e)
    logits[e] = br[e] + a[0] * Wr[0 * NEXP + e] + a[1] * Wr[1 * NEXP + e] + a[2] * Wr[2 * NEXP + e];
  float m = logits[0]; int am = 0;
#pragma unroll
  for (int e = 1; e < NEXP; ++e)
    if (logits[e] > m) { m = logits[e]; am = e; }
  float s = 0.f;
#pragma unroll
  for (int e = 0; e < NEXP; ++e) s += expf(logits[e] - m);
  scale[i] = 1.0f / s;
  int pos = atomicAdd(&cnt[am], 1);
  list[am * NTOK + pos] = i;
}

// ---------------- setup: padded offsets, row-block expert map, gathered list ----
__global__ __launch_bounds__(256) void setup_kernel(
    const int* __restrict__ cnt, const int* __restrict__ list,
    int* __restrict__ rbexp, int* __restrict__ glist) {
  __shared__ int sp[NEXP], srb[NEXP], sc[NEXP];
  if (threadIdx.x == 0) {
    int off = 0, rb = 0;
    for (int e = 0; e < NEXP; ++e) {
      sp[e] = off; srb[e] = rb; sc[e] = cnt[e];
      int nb = (sc[e] + 255) >> 8;
      off += nb << 8; rb += nb;
    }
  }
  __syncthreads();
  for (int rb = threadIdx.x; rb < NRB_MAX; rb += 256) {
    int e2 = -1;
    for (int q = 0; q < NEXP; ++q) {
      int nb = (sc[q] + 255) >> 8;
      if (rb >= srb[q] && rb < srb[q] + nb) e2 = q;
    }
    rbexp[rb] = e2;
  }
  for (int p = threadIdx.x; p < NPAD; p += 256) {
    int v = -1;
    for (int q = 0; q < NEXP; ++q) {
      int nb = (sc[q] + 255) >> 8;
      int i = p - sp[q];
      if (i >= 0 && i < (nb << 8)) v = (i < sc[q]) ? list[q * NTOK + i] : -1;
    }
    glist[p] = v;
  }
}

// ---------------- gather x (f32) -> xg (bf16, padded expert-sorted rows) ----
__global__ __launch_bounds__(256) void gather_kernel(
    const float* __restrict__ x, const int* __restrict__ glist,
    uint4* __restrict__ xg) {
  int idx = blockIdx.x * 256 + threadIdx.x;      // one per 8 elements
  if (idx >= NPAD * (DIM / 8)) return;
  int p = idx >> 6;                               // DIM/8 = 64
  int c = (idx & 63) * 8;
  int tok = glist[p];
  uint4 o = {0u, 0u, 0u, 0u};
  if (tok >= 0) {
    const float* s = x + (size_t)tok * DIM + c;
    float4 v0 = *(const float4*)s;
    float4 v1 = *(const float4*)(s + 4);
    o.x = (u32)f2b(v0.x) | ((u32)f2b(v0.y) << 16);
    o.y = (u32)f2b(v0.z) | ((u32)f2b(v0.w) << 16);
    o.z = (u32)f2b(v1.x) | ((u32)f2b(v1.y) << 16);
    o.w = (u32)f2b(v1.z) | ((u32)f2b(v1.w) << 16);
  }
  xg[idx] = o;
}

// ---------------- transpose fp32 [e][R][C] -> bf16 [e][C][R] ----------------
__global__ __launch_bounds__(256) void transpose_bf16_kernel(
    const float* __restrict__ in, unsigned short* __restrict__ out, int R, int C) {
  int e = blockIdx.z;
  in  += (size_t)e * R * C;
  out += (size_t)e * R * C;
  __shared__ float tile[32][33];
  int c0 = blockIdx.x * 32, r0 = blockIdx.y * 32;
  int tr = threadIdx.x >> 5;
  int tc = threadIdx.x & 31;
#pragma unroll
  for (int it = 0; it < 4; ++it)
    tile[tr + it * 8][tc] = in[(size_t)(r0 + tr + it * 8) * C + c0 + tc];
  __syncthreads();
#pragma unroll
  for (int it = 0; it < 4; ++it)
    out[(size_t)(c0 + tr + it * 8) * R + r0 + tc] = f2b(tile[tc][tr + it * 8]);
}

// ---------------- grouped GEMM: 256x256 tile, BK=64, 4-phase band pipeline ----
__device__ __forceinline__ void load_lds16(const void* g, void* l) {
  __builtin_amdgcn_global_load_lds(
      (const __attribute__((address_space(1))) u32*)g,
      (__attribute__((address_space(3))) u32*)l, 16, 0, 0);
}

// C[p, n] = sum_k A[p, k] * Bt[e][n][k]   (A rows gathered-contiguous)
// 8 waves 2(M)x4(N); per-wave 128x64 = 8x4 frags of 16x16x32.
// LDS 128KB: buffer P (K-tile parity) at P*64KB; A-band mh @ +mh*16KB,
// B-band nh @ +32KB+nh*16KB. Band = rows {h*64..+64} u {128+h*64..+64} (A)
// or 4x32-row strips (B), 128 rows x 64k bf16 = 16KB, 8-slot XOR swizzle.
template <int KK, int NN, bool G1, int SPLITK>
__global__ __launch_bounds__(512, 1) void moe_gemm_kernel(
    const unsigned short* __restrict__ A,    // bf16 [NPAD][KK]
    const unsigned short* __restrict__ Bt,   // bf16 [E][NN][KK]
    const float* __restrict__ bias,          // [E][NN]
    const int* __restrict__ rbexp,           // [NRB_MAX]
    const int* __restrict__ glist,           // [NPAD]
    const float* __restrict__ scale,         // [NTOK]
    unsigned short* __restrict__ Hout,       // bf16 [NPAD][FDIM] (G1)
    float* __restrict__ Yout) {              // f32  [NTOK][DIM]  (!G1, atomic)
  const int e = rbexp[blockIdx.y];
  if (e < 0) return;
  const int chunk = blockIdx.z;
  const int r0 = blockIdx.y * 256;
  const int n0 = blockIdx.x * 256;
  const int tid = threadIdx.x;
  const int lane = tid & 63;
  const int wid = tid >> 6;
  const int wm = wid >> 2;           // 0..1
  const int wn = wid & 3;            // 0..3

  constexpr int KC = KK / SPLITK;
  constexpr int NT = KC / 64;        // K-tiles
  const int k_base = chunk * KC;

  __shared__ __align__(16) char SM[131072];

  const unsigned short* Be = Bt + (size_t)e * NN * KK;

  // staging source element-offsets (8-slot XOR swizzle, inverse on source)
  int a_src[2][2], b_src[2][2];      // [load j][band h]
#pragma unroll
  for (int j = 0; j < 2; ++j) {
    int o = j * 8192 + tid * 16;     // linear byte offset within a 16KB band
    int wr = o >> 7;                 // 0..127
    int sl = ((o >> 4) & 7) ^ (wr & 7);
#pragma unroll
    for (int h = 0; h < 2; ++h) {
      int ar = r0 + (wr & 63) + h * 64 + (wr >> 6) * 128;
      a_src[j][h] = ar * KK + sl * 8 + k_base;
      int br = n0 + (wr & 31) + h * 32 + (wr >> 5) * 64;
      b_src[j][h] = br * KK + sl * 8 + k_base;
    }
  }
  const int stago = tid * 16;

  // ds_read byte offsets (within a buffer)
  int a_row[8], b_row[4], so[2];
#pragma unroll
  for (int mi = 0; mi < 8; ++mi) {
    int wr = (mi & 3) * 16 + (lane & 15) + wm * 64;
    a_row[mi] = (mi >> 2) * 16384 + wr * 128;
  }
#pragma unroll
  for (int ni = 0; ni < 4; ++ni) {
    int wr = (ni & 1) * 16 + (lane & 15) + wn * 32;
    b_row[ni] = 32768 + (ni >> 1) * 16384 + wr * 128;
  }
#pragma unroll
  for (int kk = 0; kk < 2; ++kk)
    so[kk] = ((kk * 4 + (lane >> 4)) ^ (lane & 7)) * 16;

  f32x4 acc[8][4];
#pragma unroll
  for (int i = 0; i < 8; ++i)
#pragma unroll
    for (int j = 0; j < 4; ++j) acc[i][j] = (f32x4){0.f, 0.f, 0.f, 0.f};

#define STAGE_A(kt, h)                                                      \
  { char* dst = SM + ((kt) & 1) * 65536 + (h) * 16384;                      \
    int ko = (kt) * 64;                                                     \
    load_lds16(A + a_src[0][h] + ko, dst + stago);                          \
    load_lds16(A + a_src[1][h] + ko, dst + 8192 + stago); }

#define STAGE_B(kt, h)                                                      \
  { char* dst = SM + ((kt) & 1) * 65536 + 32768 + (h) * 16384;              \
    int ko = (kt) * 64;                                                     \
    load_lds16(Be + b_src[0][h] + ko, dst + stago);                         \
    load_lds16(Be + b_src[1][h] + ko, dst + 8192 + stago); }

#define PHASE(P, mh, nh)                                                    \
  { const char* base = SM + (P) * 65536;                                    \
    bf16x8 afr[2][4], bfr[2][2];                                            \
    _Pragma("unroll") for (int kk = 0; kk < 2; ++kk) {                      \
      _Pragma("unroll") for (int q = 0; q < 4; ++q)                         \
        afr[kk][q] = *(const bf16x8*)(base + a_row[(mh) * 4 + q] + so[kk]); \
      _Pragma("unroll") for (int r = 0; r < 2; ++r)                         \
        bfr[kk][r] = *(const bf16x8*)(base + b_row[(nh) * 2 + r] + so[kk]); \
    }                                                                       \
    __builtin_amdgcn_s_setprio(1);                                          \
    _Pragma("unroll") for (int kk = 0; kk < 2; ++kk)                        \
    _Pragma("unroll") for (int q = 0; q < 4; ++q)                           \
    _Pragma("unroll") for (int r = 0; r < 2; ++r)                           \
      acc[(mh) * 4 + q][(nh) * 2 + r] = __builtin_amdgcn_mfma_f32_16x16x32_bf16( \
          afr[kk][q], bfr[kk][r], acc[(mh) * 4 + q][(nh) * 2 + r], 0, 0, 0);\
    __builtin_amdgcn_s_setprio(0); }

  // prologue: tile 0 fully staged + drained (once)
  asm volatile("s_waitcnt vmcnt(0)" ::: "memory");
  STAGE_A(0, 0) STAGE_B(0, 0) STAGE_B(0, 1) STAGE_A(0, 1)
  asm volatile("s_waitcnt vmcnt(0)" ::: "memory");
  __builtin_amdgcn_s_barrier();

  for (int t = 0; t < NT; ++t) {
    const int P = t & 1;
    const bool more = (t + 1 < NT);
    // p1: stage A0(t+1) | compute quadrant (0,0)
    if (more) STAGE_A(t + 1, 0)
    PHASE(P, 0, 0)
    __builtin_amdgcn_sched_barrier(0);
    // p2: stage B0(t+1) | compute (0,1); counted wait retires A1(t)
    if (more) STAGE_B(t + 1, 0)
    PHASE(P, 0, 1)
    asm volatile("s_waitcnt vmcnt(4)" ::: "memory");
    __builtin_amdgcn_s_barrier();
    __builtin_amdgcn_sched_barrier(0);
    // p3: stage B1(t+1) | compute (1,0)
    if (more) STAGE_B(t + 1, 1)
    PHASE(P, 1, 0)
    __builtin_amdgcn_sched_barrier(0);
    // p4: stage A1(t+1) | compute (1,1); counted wait retires A0,B0,B1(t+1)
    if (more) STAGE_A(t + 1, 1)
    PHASE(P, 1, 1)
    asm volatile("s_waitcnt vmcnt(2)" ::: "memory");
    __builtin_amdgcn_s_barrier();
    __builtin_amdgcn_sched_barrier(0);
  }
#undef STAGE_A
#undef STAGE_B
#undef PHASE

  // epilogue: frag D layout col = lane&15, row = (lane>>4)*4 + i
  const int colb = n0 + wn * 64 + (lane & 15);
  float bia[4];
#pragma unroll
  for (int ni = 0; ni < 4; ++ni) bia[ni] = bias[(size_t)e * NN + colb + ni * 16];
#pragma unroll
  for (int mi = 0; mi < 8; ++mi) {
#pragma unroll
    for (int i = 0; i < 4; ++i) {
      int p = r0 + wm * 128 + mi * 16 + (lane >> 4) * 4 + i;
      if constexpr (G1) {
#pragma unroll
        for (int ni = 0; ni < 4; ++ni) {
          float v = acc[mi][ni][i] + bia[ni];
          float g = 0.5f * v * (1.0f + erff(v * 0.70710678118654752f));
          Hout[(size_t)p * NN + colb + ni * 16] = f2b(g);
        }
      } else {
        int tok = glist[p];
        if (tok >= 0) {
          float s = scale[tok];
#pragma unroll
          for (int ni = 0; ni < 4; ++ni) {
            float v = acc[mi][ni][i] + (chunk == 0 ? bia[ni] : 0.0f);
            unsafeAtomicAdd(&Yout[(size_t)tok * NN + colb + ni * 16], v * s);
          }
        }
      }
    }
  }
}

extern "C" void kernel_launch(void* const* d_in, const int* in_sizes, int n_in,
                              void* d_out, int out_size, void* d_ws, size_t ws_size,
                              hipStream_t stream) {
  const float* x    = (const float*)d_in[0];
  const float* attr = (const float*)d_in[1];
  const float* Wr   = (const float*)d_in[2];
  const float* br   = (const float*)d_in[3];
  const float* W1   = (const float*)d_in[4];
  const float* b1   = (const float*)d_in[5];
  const float* W2   = (const float*)d_in[6];
  const float* b2   = (const float*)d_in[7];
  float* out = (float*)d_out;
  char* ws = (char*)d_ws;

  unsigned short* WT  = (unsigned short*)(ws + OFF_WT);
  unsigned short* xg  = (unsigned short*)(ws + OFF_XG);
  unsigned short* H   = (unsigned short*)(ws + OFF_H);
  float* scale        = (float*)(ws + OFF_SCALE);
  int* cnt            = (int*)(ws + OFF_CNT);
  int* rbexp          = (int*)(ws + OFF_RBEXP);
  int* list           = (int*)(ws + OFF_LIST);
  int* glist          = (int*)(ws + OFF_GLIST);

  hipMemsetAsync(cnt, 0, NEXP * sizeof(int), stream);
  hipMemsetAsync(out, 0, (size_t)out_size * sizeof(float), stream);
  router_kernel<<<NTOK / 256, 256, 0, stream>>>(attr, Wr, br, scale, cnt, list);
  setup_kernel<<<1, 256, 0, stream>>>(cnt, list, rbexp, glist);
  gather_kernel<<<(NPAD * (DIM / 8)) / 256, 256, 0, stream>>>(x, glist, (uint4*)xg);

  // W1 [E][512][2048] -> W1t [E][2048][512]
  transpose_bf16_kernel<<<dim3(FDIM / 32, DIM / 32, NEXP), 256, 0, stream>>>(W1, WT, DIM, FDIM);
  // GEMM1: H = gelu(xg @ W1 + b1), K=512 (8 K-tiles)
  moe_gemm_kernel<DIM, FDIM, true, 1><<<dim3(FDIM / 256, NRB_MAX, 1), 512, 0, stream>>>(
      xg, WT, b1, rbexp, glist, scale, H, nullptr);
  // W2 [E][2048][512] -> W2t [E][512][2048]  (reuses WT region)
  transpose_bf16_kernel<<<dim3(DIM / 32, FDIM / 32, NEXP), 256, 0, stream>>>(W2, WT, FDIM, DIM);
  // GEMM2: out = (H @ W2 + b2) * scale, K=2048 split 4 ways (8 K-tiles each)
  moe_gemm_kernel<FDIM, DIM, false, 4><<<dim3(DIM / 256, NRB_MAX, 4), 512, 0, stream>>>(
      H, WT, b2, rbexp, glist, scale, nullptr, out);
}

// Round 6
// 245.479 us; speedup vs baseline: 1.0959x; 1.0959x over previous
//
#include <hip/hip_runtime.h>
#include <hip/hip_bf16.h>

typedef unsigned int u32;
typedef __bf16 bf16x8 __attribute__((ext_vector_type(8)));
typedef float  f32x4  __attribute__((ext_vector_type(4)));

#define NTOK 8192
#define DIM  512
#define FDIM 2048
#define NEXP 8
#define NRB_MAX 72                     // max 128-row blocks after per-expert padding
#define NPAD (NRB_MAX * 128)           // 9216 padded rows

// ---- workspace layout (bytes) ----
// WT region shared: W1t before GEMM1, overwritten by W2t after GEMM1.
#define OFF_WT    0ull                 // bf16 16,777,216 B
#define OFF_XG    16777216ull          // bf16 [NPAD][DIM]    9,437,184 B
#define OFF_H     26214400ull          // bf16 [NPAD][FDIM]  37,748,736 B
#define OFF_SCALE 63963136ull          // f32  [NTOK]            32,768 B
#define OFF_CNT   63995904ull          // int  [E]
#define OFF_RBEXP 63996032ull          // int  [NRB_MAX]
#define OFF_LIST  63996416ull          // int  [E][NTOK]        262,144 B
#define OFF_GLIST 64258560ull          // int  [NPAD]            36,864 B

__device__ __forceinline__ u32 rotl32(u32 x, int r) { return (x << r) | (x >> (32 - r)); }

__device__ __forceinline__ void threefry2x32(u32 k0, u32 k1, u32 x0, u32 x1,
                                             u32& y0, u32& y1) {
  u32 ks2 = k0 ^ k1 ^ 0x1BD11BDAu;
  x0 += k0; x1 += k1;
#define TF_RND(r) { x0 += x1; x1 = rotl32(x1, r); x1 ^= x0; }
  TF_RND(13) TF_RND(15) TF_RND(26) TF_RND(6)
  x0 += k1;  x1 += ks2 + 1u;
  TF_RND(17) TF_RND(29) TF_RND(16) TF_RND(24)
  x0 += ks2; x1 += k0 + 2u;
  TF_RND(13) TF_RND(15) TF_RND(26) TF_RND(6)
  x0 += k0;  x1 += k1 + 3u;
  TF_RND(17) TF_RND(29) TF_RND(16) TF_RND(24)
  x0 += k1;  x1 += ks2 + 4u;
  TF_RND(13) TF_RND(15) TF_RND(26) TF_RND(6)
  x0 += ks2; x1 += k0 + 5u;
#undef TF_RND
  y0 = x0; y1 = x1;
}

__device__ __forceinline__ float jax_uniform(u32 j) {
  u32 y0, y1;
  threefry2x32(0u, 42u, 0u, j, y0, y1);
  u32 bits = y0 ^ y1;
  return __uint_as_float((bits >> 9) | 0x3F800000u) - 1.0f;
}

__device__ __forceinline__ unsigned short f2b(float f) {
  u32 u = __float_as_uint(f);
  u32 r = (u + 0x7FFFu + ((u >> 16) & 1u)) >> 16;
  return (unsigned short)r;
}

// ---------------- router ----------------
__global__ __launch_bounds__(256) void router_kernel(
    const float* __restrict__ attr, const float* __restrict__ Wr,
    const float* __restrict__ br, float* __restrict__ scale,
    int* __restrict__ cnt, int* __restrict__ list) {
  int i = blockIdx.x * 256 + threadIdx.x;
  if (i >= NTOK) return;
  float a[3];
#pragma unroll
  for (int c = 0; c < 3; ++c) {
    float u = jax_uniform((u32)(3 * i + c));
    a[c] = attr[3 * i + c] * ((1.0f + 0.01f) - 2.0f * 0.01f * u);
  }
  float logits[NEXP];
#pragma unroll
  for (int e = 0; e < NEXP; ++e)
    logits[e] = br[e] + a[0] * Wr[0 * NEXP + e] + a[1] * Wr[1 * NEXP + e] + a[2] * Wr[2 * NEXP + e];
  float m = logits[0]; int am = 0;
#pragma unroll
  for (int e = 1; e < NEXP; ++e)
    if (logits[e] > m) { m = logits[e]; am = e; }
  float s = 0.f;
#pragma unroll
  for (int e = 0; e < NEXP; ++e) s += expf(logits[e] - m);
  scale[i] = 1.0f / s;
  int pos = atomicAdd(&cnt[am], 1);
  list[am * NTOK + pos] = i;
}

// ---------------- setup: 128-row padded segments per expert ----------------
__global__ __launch_bounds__(256) void setup_kernel(
    const int* __restrict__ cnt, const int* __restrict__ list,
    int* __restrict__ rbexp, int* __restrict__ glist) {
  __shared__ int sp[NEXP], srb[NEXP], sc[NEXP];
  if (threadIdx.x == 0) {
    int off = 0, rb = 0;
    for (int e = 0; e < NEXP; ++e) {
      sp[e] = off; srb[e] = rb; sc[e] = cnt[e];
      int nb = (sc[e] + 127) >> 7;
      off += nb << 7; rb += nb;
    }
  }
  __syncthreads();
  for (int rb = threadIdx.x; rb < NRB_MAX; rb += 256) {
    int e2 = -1;
    for (int q = 0; q < NEXP; ++q) {
      int nb = (sc[q] + 127) >> 7;
      if (rb >= srb[q] && rb < srb[q] + nb) e2 = q;
    }
    rbexp[rb] = e2;
  }
  for (int p = threadIdx.x; p < NPAD; p += 256) {
    int v = -1;
    for (int q = 0; q < NEXP; ++q) {
      int nb = (sc[q] + 127) >> 7;
      int i = p - sp[q];
      if (i >= 0 && i < (nb << 7)) v = (i < sc[q]) ? list[q * NTOK + i] : -1;
    }
    glist[p] = v;
  }
}

// ---------------- gather x (f32) -> xg (bf16, padded expert-sorted rows) ----
__global__ __launch_bounds__(256) void gather_kernel(
    const float* __restrict__ x, const int* __restrict__ glist,
    uint4* __restrict__ xg) {
  int idx = blockIdx.x * 256 + threadIdx.x;      // one per 8 elements
  if (idx >= NPAD * (DIM / 8)) return;
  int p = idx >> 6;                               // DIM/8 = 64
  int c = (idx & 63) * 8;
  int tok = glist[p];
  uint4 o = {0u, 0u, 0u, 0u};
  if (tok >= 0) {
    const float* s = x + (size_t)tok * DIM + c;
    float4 v0 = *(const float4*)s;
    float4 v1 = *(const float4*)(s + 4);
    o.x = (u32)f2b(v0.x) | ((u32)f2b(v0.y) << 16);
    o.y = (u32)f2b(v0.z) | ((u32)f2b(v0.w) << 16);
    o.z = (u32)f2b(v1.x) | ((u32)f2b(v1.y) << 16);
    o.w = (u32)f2b(v1.z) | ((u32)f2b(v1.w) << 16);
  }
  xg[idx] = o;
}

// ---------------- transpose fp32 [e][R][C] -> bf16 [e][C][R] ----------------
__global__ __launch_bounds__(256) void transpose_bf16_kernel(
    const float* __restrict__ in, unsigned short* __restrict__ out, int R, int C) {
  int e = blockIdx.z;
  in  += (size_t)e * R * C;
  out += (size_t)e * R * C;
  __shared__ float tile[32][33];
  int c0 = blockIdx.x * 32, r0 = blockIdx.y * 32;
  int tr = threadIdx.x >> 5;
  int tc = threadIdx.x & 31;
#pragma unroll
  for (int it = 0; it < 4; ++it)
    tile[tr + it * 8][tc] = in[(size_t)(r0 + tr + it * 8) * C + c0 + tc];
  __syncthreads();
#pragma unroll
  for (int it = 0; it < 4; ++it)
    out[(size_t)(c0 + tr + it * 8) * R + r0 + tc] = f2b(tile[tc][tr + it * 8]);
}

// ---------------- grouped GEMM (r2-verified loop, dense grid, 5 blk/CU) ------
__device__ __forceinline__ void load_lds16(const void* g, void* l) {
  __builtin_amdgcn_global_load_lds(
      (const __attribute__((address_space(1))) u32*)g,
      (__attribute__((address_space(3))) u32*)l, 16, 0, 0);
}

// C[p, n] = sum_k A[p, k] * Bt[e][n][k]   (A rows gathered-contiguous)
// 128x128 tile, BK=32, 4 waves (2x2), per-wave 64x64 (4x4 16x16x32 frags).
// LDS 32 KB double-buffered -> 5 blocks/CU; __launch_bounds__(256,5).
template <int KK, int NN, bool G1, int SPLITK>
__global__ __launch_bounds__(256, 5) void moe_gemm_kernel(
    const unsigned short* __restrict__ A,    // bf16 [NPAD][KK]
    const unsigned short* __restrict__ Bt,   // bf16 [E][NN][KK]
    const float* __restrict__ bias,          // [E][NN]
    const int* __restrict__ rbexp,           // [NRB_MAX]
    const int* __restrict__ glist,           // [NPAD]
    const float* __restrict__ scale,         // [NTOK]
    unsigned short* __restrict__ Hout,       // bf16 [NPAD][FDIM] (G1)
    float* __restrict__ Yout) {              // f32  [NTOK][DIM]  (!G1, atomic)
  const int e = rbexp[blockIdx.y];
  if (e < 0) return;
  const int chunk = blockIdx.z;
  const int r0 = blockIdx.y * 128;
  const int n0 = blockIdx.x * 128;
  const int tid = threadIdx.x;
  const int lane = tid & 63;
  const int wid = tid >> 6;
  const int wm = wid >> 1, wn = wid & 1;

  constexpr int KC = KK / SPLITK;      // K per chunk
  constexpr int NSTEP = KC / 32;
  const int k_base = chunk * KC;

  // buffer b at byte offset b*16384; within buffer: A tile @0 (8KB), B @8192
  __shared__ __align__(16) char SM[2 * 16384];

  const unsigned short* Be = Bt + (size_t)e * NN * KK;

  // staging source offsets (XOR slot-swizzled LDS layout, inverse on source)
  int aoff[2], boff[2], ldso[2];
#pragma unroll
  for (int j = 0; j < 2; ++j) {
    int o = j * 4096 + tid * 16;       // linear LDS byte offset within 8 KB tile
    int row = o >> 6;                  // 0..127
    int slot = (o >> 4) & 3;
    int g = (slot - (row >> 1)) & 3;   // which 8-elem k-group lives here
    aoff[j] = (r0 + row) * KK + g * 8 + k_base;
    boff[j] = (n0 + row) * KK + g * 8 + k_base;
    ldso[j] = o;
  }

  f32x4 acc[4][4];
#pragma unroll
  for (int i = 0; i < 4; ++i)
#pragma unroll
    for (int j = 0; j < 4; ++j) acc[i][j] = (f32x4){0.f, 0.f, 0.f, 0.f};

  int a_addr[4], b_addr[4];                 // byte offsets within a tile
#pragma unroll
  for (int mi = 0; mi < 4; ++mi) {
    int row = wm * 64 + mi * 16 + (lane & 15);
    int gp = ((lane >> 4) + (row >> 1)) & 3;
    a_addr[mi] = (row * 32 + gp * 8) * 2;
  }
#pragma unroll
  for (int ni = 0; ni < 4; ++ni) {
    int row = wn * 64 + ni * 16 + (lane & 15);
    int gp = ((lane >> 4) + (row >> 1)) & 3;
    b_addr[ni] = (row * 32 + gp * 8) * 2;
  }

#define STAGE(kt, b)                                                        \
  {                                                                         \
    int koff = (kt) * 32;                                                   \
    char* base = (char*)SM + (b) * 16384;                                   \
    _Pragma("unroll")                                                       \
    for (int j = 0; j < 2; ++j) {                                           \
      load_lds16(A + aoff[j] + koff, base + ldso[j]);                       \
      load_lds16(Be + boff[j] + koff, base + 8192 + ldso[j]);               \
    }                                                                       \
  }

#define COMPUTE(b)                                                          \
  {                                                                         \
    const char* base = (const char*)SM + (b) * 16384;                       \
    bf16x8 af[4], bfr[4];                                                   \
    _Pragma("unroll")                                                       \
    for (int mi = 0; mi < 4; ++mi) af[mi] = *(const bf16x8*)(base + a_addr[mi]); \
    _Pragma("unroll")                                                       \
    for (int ni = 0; ni < 4; ++ni) bfr[ni] = *(const bf16x8*)(base + 8192 + b_addr[ni]); \
    _Pragma("unroll")                                                       \
    for (int mi = 0; mi < 4; ++mi)                                          \
      _Pragma("unroll")                                                     \
      for (int ni = 0; ni < 4; ++ni)                                        \
        acc[mi][ni] = __builtin_amdgcn_mfma_f32_16x16x32_bf16(af[mi], bfr[ni], acc[mi][ni], 0, 0, 0); \
  }

  // 2-phase pipeline: stage(t+1) BEFORE compute(t); one vmcnt(0)+barrier per step.
  STAGE(0, 0)
  __syncthreads();
  int cur = 0;
  for (int kt = 0; kt < NSTEP - 1; ++kt) {
    STAGE(kt + 1, cur ^ 1)
    COMPUTE(cur)
    __syncthreads();
    cur ^= 1;
  }
  COMPUTE(cur)
#undef STAGE
#undef COMPUTE

  // epilogue: frag D layout col = lane&15, row = (lane>>4)*4 + i
  const int colb = n0 + wn * 64 + (lane & 15);
  float bia[4];
#pragma unroll
  for (int ni = 0; ni < 4; ++ni) bia[ni] = bias[(size_t)e * NN + colb + ni * 16];
#pragma unroll
  for (int mi = 0; mi < 4; ++mi) {
#pragma unroll
    for (int i = 0; i < 4; ++i) {
      int p = r0 + wm * 64 + mi * 16 + (lane >> 4) * 4 + i;
      if constexpr (G1) {
#pragma unroll
        for (int ni = 0; ni < 4; ++ni) {
          float v = acc[mi][ni][i] + bia[ni];
          float g = 0.5f * v * (1.0f + erff(v * 0.70710678118654752f));
          Hout[(size_t)p * NN + colb + ni * 16] = f2b(g);
        }
      } else {
        int tok = glist[p];
        if (tok >= 0) {
          float s = scale[tok];
#pragma unroll
          for (int ni = 0; ni < 4; ++ni) {
            float v = acc[mi][ni][i] + (chunk == 0 ? bia[ni] : 0.0f);
            unsafeAtomicAdd(&Yout[(size_t)tok * NN + colb + ni * 16], v * s);
          }
        }
      }
    }
  }
}

extern "C" void kernel_launch(void* const* d_in, const int* in_sizes, int n_in,
                              void* d_out, int out_size, void* d_ws, size_t ws_size,
                              hipStream_t stream) {
  const float* x    = (const float*)d_in[0];
  const float* attr = (const float*)d_in[1];
  const float* Wr   = (const float*)d_in[2];
  const float* br   = (const float*)d_in[3];
  const float* W1   = (const float*)d_in[4];
  const float* b1   = (const float*)d_in[5];
  const float* W2   = (const float*)d_in[6];
  const float* b2   = (const float*)d_in[7];
  float* out = (float*)d_out;
  char* ws = (char*)d_ws;

  unsigned short* WT  = (unsigned short*)(ws + OFF_WT);
  unsigned short* xg  = (unsigned short*)(ws + OFF_XG);
  unsigned short* H   = (unsigned short*)(ws + OFF_H);
  float* scale        = (float*)(ws + OFF_SCALE);
  int* cnt            = (int*)(ws + OFF_CNT);
  int* rbexp          = (int*)(ws + OFF_RBEXP);
  int* list           = (int*)(ws + OFF_LIST);
  int* glist          = (int*)(ws + OFF_GLIST);

  hipMemsetAsync(cnt, 0, NEXP * sizeof(int), stream);
  hipMemsetAsync(out, 0, (size_t)out_size * sizeof(float), stream);
  router_kernel<<<NTOK / 256, 256, 0, stream>>>(attr, Wr, br, scale, cnt, list);
  setup_kernel<<<1, 256, 0, stream>>>(cnt, list, rbexp, glist);
  gather_kernel<<<(NPAD * (DIM / 8)) / 256, 256, 0, stream>>>(x, glist, (uint4*)xg);

  // W1 [E][512][2048] -> W1t [E][2048][512]
  transpose_bf16_kernel<<<dim3(FDIM / 32, DIM / 32, NEXP), 256, 0, stream>>>(W1, WT, DIM, FDIM);
  // GEMM1: H = gelu(xg @ W1 + b1), K=512, dense 16x72 grid
  moe_gemm_kernel<DIM, FDIM, true, 1><<<dim3(FDIM / 128, NRB_MAX, 1), 256, 0, stream>>>(
      xg, WT, b1, rbexp, glist, scale, H, nullptr);
  // W2 [E][2048][512] -> W2t [E][512][2048]  (reuses WT region)
  transpose_bf16_kernel<<<dim3(DIM / 32, FDIM / 32, NEXP), 256, 0, stream>>>(W2, WT, FDIM, DIM);
  // GEMM2: out = (H @ W2 + b2) * scale, K=2048 split 4 ways, dense 4x72x4 grid
  moe_gemm_kernel<FDIM, DIM, false, 4><<<dim3(DIM / 128, NRB_MAX, 4), 256, 0, stream>>>(
      H, WT, b2, rbexp, glist, scale, nullptr, out);
}

// Round 7
// 205.777 us; speedup vs baseline: 1.3073x; 1.1929x over previous
//
#include <hip/hip_runtime.h>
#include <hip/hip_bf16.h>

typedef unsigned int u32;
typedef __bf16 bf16x8 __attribute__((ext_vector_type(8)));
typedef float  f32x4  __attribute__((ext_vector_type(4)));

#define NTOK 8192
#define DIM  512
#define FDIM 2048
#define NEXP 8
#define NRB_MAX 72                     // max 128-row blocks after per-expert padding
#define NPAD (NRB_MAX * 128)           // 9216 padded rows

// ---- workspace layout (bytes) ----
// WT region shared: W1t before GEMM1, overwritten by W2t after GEMM1.
#define OFF_WT    0ull                 // bf16 16,777,216 B
#define OFF_XG    16777216ull          // bf16 [NPAD][DIM]    9,437,184 B
#define OFF_H     26214400ull          // bf16 [NPAD][FDIM]  37,748,736 B
#define OFF_SCALE 63963136ull          // f32  [NTOK]            32,768 B
#define OFF_CNT   63995904ull          // int  [E]
#define OFF_RBEXP 63996032ull          // int  [NRB_MAX]
#define OFF_LIST  63996416ull          // int  [E][NTOK]        262,144 B
#define OFF_GLIST 64258560ull          // int  [NPAD]            36,864 B

__device__ __forceinline__ u32 rotl32(u32 x, int r) { return (x << r) | (x >> (32 - r)); }

__device__ __forceinline__ void threefry2x32(u32 k0, u32 k1, u32 x0, u32 x1,
                                             u32& y0, u32& y1) {
  u32 ks2 = k0 ^ k1 ^ 0x1BD11BDAu;
  x0 += k0; x1 += k1;
#define TF_RND(r) { x0 += x1; x1 = rotl32(x1, r); x1 ^= x0; }
  TF_RND(13) TF_RND(15) TF_RND(26) TF_RND(6)
  x0 += k1;  x1 += ks2 + 1u;
  TF_RND(17) TF_RND(29) TF_RND(16) TF_RND(24)
  x0 += ks2; x1 += k0 + 2u;
  TF_RND(13) TF_RND(15) TF_RND(26) TF_RND(6)
  x0 += k0;  x1 += k1 + 3u;
  TF_RND(17) TF_RND(29) TF_RND(16) TF_RND(24)
  x0 += k1;  x1 += ks2 + 4u;
  TF_RND(13) TF_RND(15) TF_RND(26) TF_RND(6)
  x0 += ks2; x1 += k0 + 5u;
#undef TF_RND
  y0 = x0; y1 = x1;
}

__device__ __forceinline__ float jax_uniform(u32 j) {
  u32 y0, y1;
  threefry2x32(0u, 42u, 0u, j, y0, y1);
  u32 bits = y0 ^ y1;
  return __uint_as_float((bits >> 9) | 0x3F800000u) - 1.0f;
}

__device__ __forceinline__ unsigned short f2b(float f) {
  u32 u = __float_as_uint(f);
  u32 r = (u + 0x7FFFu + ((u >> 16) & 1u)) >> 16;
  return (unsigned short)r;
}

// ---------------- router ----------------
__global__ __launch_bounds__(256) void router_kernel(
    const float* __restrict__ attr, const float* __restrict__ Wr,
    const float* __restrict__ br, float* __restrict__ scale,
    int* __restrict__ cnt, int* __restrict__ list) {
  int i = blockIdx.x * 256 + threadIdx.x;
  if (i >= NTOK) return;
  float a[3];
#pragma unroll
  for (int c = 0; c < 3; ++c) {
    float u = jax_uniform((u32)(3 * i + c));
    a[c] = attr[3 * i + c] * ((1.0f + 0.01f) - 2.0f * 0.01f * u);
  }
  float logits[NEXP];
#pragma unroll
  for (int e = 0; e < NEXP; ++e)
    logits[e] = br[e] + a[0] * Wr[0 * NEXP + e] + a[1] * Wr[1 * NEXP + e] + a[2] * Wr[2 * NEXP + e];
  float m = logits[0]; int am = 0;
#pragma unroll
  for (int e = 1; e < NEXP; ++e)
    if (logits[e] > m) { m = logits[e]; am = e; }
  float s = 0.f;
#pragma unroll
  for (int e = 0; e < NEXP; ++e) s += expf(logits[e] - m);
  scale[i] = 1.0f / s;
  int pos = atomicAdd(&cnt[am], 1);
  list[am * NTOK + pos] = i;
}

// ---------------- setup: 128-row padded segments per expert ----------------
__global__ __launch_bounds__(256) void setup_kernel(
    const int* __restrict__ cnt, const int* __restrict__ list,
    int* __restrict__ rbexp, int* __restrict__ glist) {
  __shared__ int sp[NEXP], srb[NEXP], sc[NEXP];
  if (threadIdx.x == 0) {
    int off = 0, rb = 0;
    for (int e = 0; e < NEXP; ++e) {
      sp[e] = off; srb[e] = rb; sc[e] = cnt[e];
      int nb = (sc[e] + 127) >> 7;
      off += nb << 7; rb += nb;
    }
  }
  __syncthreads();
  for (int rb = threadIdx.x; rb < NRB_MAX; rb += 256) {
    int e2 = -1;
    for (int q = 0; q < NEXP; ++q) {
      int nb = (sc[q] + 127) >> 7;
      if (rb >= srb[q] && rb < srb[q] + nb) e2 = q;
    }
    rbexp[rb] = e2;
  }
  for (int p = threadIdx.x; p < NPAD; p += 256) {
    int v = -1;
    for (int q = 0; q < NEXP; ++q) {
      int nb = (sc[q] + 127) >> 7;
      int i = p - sp[q];
      if (i >= 0 && i < (nb << 7)) v = (i < sc[q]) ? list[q * NTOK + i] : -1;
    }
    glist[p] = v;
  }
}

// ---------------- gather x (f32) -> xg (bf16, padded expert-sorted rows) ----
__global__ __launch_bounds__(256) void gather_kernel(
    const float* __restrict__ x, const int* __restrict__ glist,
    uint4* __restrict__ xg) {
  int idx = blockIdx.x * 256 + threadIdx.x;      // one per 8 elements
  if (idx >= NPAD * (DIM / 8)) return;
  int p = idx >> 6;                               // DIM/8 = 64
  int c = (idx & 63) * 8;
  int tok = glist[p];
  uint4 o = {0u, 0u, 0u, 0u};
  if (tok >= 0) {
    const float* s = x + (size_t)tok * DIM + c;
    float4 v0 = *(const float4*)s;
    float4 v1 = *(const float4*)(s + 4);
    o.x = (u32)f2b(v0.x) | ((u32)f2b(v0.y) << 16);
    o.y = (u32)f2b(v0.z) | ((u32)f2b(v0.w) << 16);
    o.z = (u32)f2b(v1.x) | ((u32)f2b(v1.y) << 16);
    o.w = (u32)f2b(v1.z) | ((u32)f2b(v1.w) << 16);
  }
  xg[idx] = o;
}

// ---------------- transpose fp32 [e][R][C] -> bf16 [e][C][R] ----------------
__global__ __launch_bounds__(256) void transpose_bf16_kernel(
    const float* __restrict__ in, unsigned short* __restrict__ out, int R, int C) {
  int e = blockIdx.z;
  in  += (size_t)e * R * C;
  out += (size_t)e * R * C;
  __shared__ float tile[32][33];
  int c0 = blockIdx.x * 32, r0 = blockIdx.y * 32;
  int tr = threadIdx.x >> 5;
  int tc = threadIdx.x & 31;
#pragma unroll
  for (int it = 0; it < 4; ++it)
    tile[tr + it * 8][tc] = in[(size_t)(r0 + tr + it * 8) * C + c0 + tc];
  __syncthreads();
#pragma unroll
  for (int it = 0; it < 4; ++it)
    out[(size_t)(c0 + tr + it * 8) * R + r0 + tc] = f2b(tile[tc][tr + it * 8]);
}

// ---------------- grouped GEMM (r2-verified loop, XCD-chunked work map) ------
__device__ __forceinline__ void load_lds16(const void* g, void* l) {
  __builtin_amdgcn_global_load_lds(
      (const __attribute__((address_space(1))) u32*)g,
      (__attribute__((address_space(3))) u32*)l, 16, 0, 0);
}

// C[p, n] = sum_k A[p, k] * Bt[e][n][k]   (A rows gathered-contiguous)
// 128x128 tile, BK=32, 4 waves (2x2), per-wave 64x64 (4x4 16x16x32 frags).
// Flat 1-D grid; bijective chunked XCD remap (m204): XCD c gets a contiguous
// wgid chunk, x-fastest, z-slowest -> A-slices single-XCD, atomics 2-XCD.
template <int KK, int NN, int NX, bool G1, int SPLITK>
__global__ __launch_bounds__(256, 5) void moe_gemm_kernel(
    const unsigned short* __restrict__ A,    // bf16 [NPAD][KK]
    const unsigned short* __restrict__ Bt,   // bf16 [E][NN][KK]
    const float* __restrict__ bias,          // [E][NN]
    const int* __restrict__ rbexp,           // [NRB_MAX]
    const int* __restrict__ glist,           // [NPAD]
    const float* __restrict__ scale,         // [NTOK]
    unsigned short* __restrict__ Hout,       // bf16 [NPAD][FDIM] (G1)
    float* __restrict__ Yout) {              // f32  [NTOK][DIM]  (!G1, atomic)
  // ---- work remap: nwg = NX*NRB_MAX*SPLITK (multiple of 8 by construction) ----
  constexpr int NWG = NX * NRB_MAX * SPLITK;
  constexpr int CHUNK = NWG / 8;
  const int xcd = blockIdx.x & 7;
  const int wgid = xcd * CHUNK + (blockIdx.x >> 3);
  const int bx = wgid % NX;
  const int by = (wgid / NX) % NRB_MAX;
  const int chunk = wgid / (NX * NRB_MAX);

  const int e = rbexp[by];
  if (e < 0) return;
  const int r0 = by * 128;
  const int n0 = bx * 128;
  const int tid = threadIdx.x;
  const int lane = tid & 63;
  const int wid = tid >> 6;
  const int wm = wid >> 1, wn = wid & 1;

  constexpr int KC = KK / SPLITK;      // K per chunk
  constexpr int NSTEP = KC / 32;
  const int k_base = chunk * KC;

  // buffer b at byte offset b*16384; within buffer: A tile @0 (8KB), B @8192
  __shared__ __align__(16) char SM[2 * 16384];

  const unsigned short* Be = Bt + (size_t)e * NN * KK;

  // staging source offsets (XOR slot-swizzled LDS layout, inverse on source)
  int aoff[2], boff[2], ldso[2];
#pragma unroll
  for (int j = 0; j < 2; ++j) {
    int o = j * 4096 + tid * 16;       // linear LDS byte offset within 8 KB tile
    int row = o >> 6;                  // 0..127
    int slot = (o >> 4) & 3;
    int g = (slot - (row >> 1)) & 3;   // which 8-elem k-group lives here
    aoff[j] = (r0 + row) * KK + g * 8 + k_base;
    boff[j] = (n0 + row) * KK + g * 8 + k_base;
    ldso[j] = o;
  }

  f32x4 acc[4][4];
#pragma unroll
  for (int i = 0; i < 4; ++i)
#pragma unroll
    for (int j = 0; j < 4; ++j) acc[i][j] = (f32x4){0.f, 0.f, 0.f, 0.f};

  int a_addr[4], b_addr[4];                 // byte offsets within a tile
#pragma unroll
  for (int mi = 0; mi < 4; ++mi) {
    int row = wm * 64 + mi * 16 + (lane & 15);
    int gp = ((lane >> 4) + (row >> 1)) & 3;
    a_addr[mi] = (row * 32 + gp * 8) * 2;
  }
#pragma unroll
  for (int ni = 0; ni < 4; ++ni) {
    int row = wn * 64 + ni * 16 + (lane & 15);
    int gp = ((lane >> 4) + (row >> 1)) & 3;
    b_addr[ni] = (row * 32 + gp * 8) * 2;
  }

#define STAGE(kt, b)                                                        \
  {                                                                         \
    int koff = (kt) * 32;                                                   \
    char* base = (char*)SM + (b) * 16384;                                   \
    _Pragma("unroll")                                                       \
    for (int j = 0; j < 2; ++j) {                                           \
      load_lds16(A + aoff[j] + koff, base + ldso[j]);                       \
      load_lds16(Be + boff[j] + koff, base + 8192 + ldso[j]);               \
    }                                                                       \
  }

#define COMPUTE(b)                                                          \
  {                                                                         \
    const char* base = (const char*)SM + (b) * 16384;                       \
    bf16x8 af[4], bfr[4];                                                   \
    _Pragma("unroll")                                                       \
    for (int mi = 0; mi < 4; ++mi) af[mi] = *(const bf16x8*)(base + a_addr[mi]); \
    _Pragma("unroll")                                                       \
    for (int ni = 0; ni < 4; ++ni) bfr[ni] = *(const bf16x8*)(base + 8192 + b_addr[ni]); \
    _Pragma("unroll")                                                       \
    for (int mi = 0; mi < 4; ++mi)                                          \
      _Pragma("unroll")                                                     \
      for (int ni = 0; ni < 4; ++ni)                                        \
        acc[mi][ni] = __builtin_amdgcn_mfma_f32_16x16x32_bf16(af[mi], bfr[ni], acc[mi][ni], 0, 0, 0); \
  }

  // 2-phase pipeline: stage(t+1) BEFORE compute(t); one vmcnt(0)+barrier per step.
  STAGE(0, 0)
  __syncthreads();
  int cur = 0;
  for (int kt = 0; kt < NSTEP - 1; ++kt) {
    STAGE(kt + 1, cur ^ 1)
    COMPUTE(cur)
    __syncthreads();
    cur ^= 1;
  }
  COMPUTE(cur)
#undef STAGE
#undef COMPUTE

  // epilogue: frag D layout col = lane&15, row = (lane>>4)*4 + i
  const int colb = n0 + wn * 64 + (lane & 15);
  float bia[4];
#pragma unroll
  for (int ni = 0; ni < 4; ++ni) bia[ni] = bias[(size_t)e * NN + colb + ni * 16];
#pragma unroll
  for (int mi = 0; mi < 4; ++mi) {
#pragma unroll
    for (int i = 0; i < 4; ++i) {
      int p = r0 + wm * 64 + mi * 16 + (lane >> 4) * 4 + i;
      if constexpr (G1) {
#pragma unroll
        for (int ni = 0; ni < 4; ++ni) {
          float v = acc[mi][ni][i] + bia[ni];
          float g = 0.5f * v * (1.0f + erff(v * 0.70710678118654752f));
          Hout[(size_t)p * NN + colb + ni * 16] = f2b(g);
        }
      } else {
        int tok = glist[p];
        if (tok >= 0) {
          float s = scale[tok];
#pragma unroll
          for (int ni = 0; ni < 4; ++ni) {
            float v = acc[mi][ni][i] + (chunk == 0 ? bia[ni] : 0.0f);
            unsafeAtomicAdd(&Yout[(size_t)tok * NN + colb + ni * 16], v * s);
          }
        }
      }
    }
  }
}

extern "C" void kernel_launch(void* const* d_in, const int* in_sizes, int n_in,
                              void* d_out, int out_size, void* d_ws, size_t ws_size,
                              hipStream_t stream) {
  const float* x    = (const float*)d_in[0];
  const float* attr = (const float*)d_in[1];
  const float* Wr   = (const float*)d_in[2];
  const float* br   = (const float*)d_in[3];
  const float* W1   = (const float*)d_in[4];
  const float* b1   = (const float*)d_in[5];
  const float* W2   = (const float*)d_in[6];
  const float* b2   = (const float*)d_in[7];
  float* out = (float*)d_out;
  char* ws = (char*)d_ws;

  unsigned short* WT  = (unsigned short*)(ws + OFF_WT);
  unsigned short* xg  = (unsigned short*)(ws + OFF_XG);
  unsigned short* H   = (unsigned short*)(ws + OFF_H);
  float* scale        = (float*)(ws + OFF_SCALE);
  int* cnt            = (int*)(ws + OFF_CNT);
  int* rbexp          = (int*)(ws + OFF_RBEXP);
  int* list           = (int*)(ws + OFF_LIST);
  int* glist          = (int*)(ws + OFF_GLIST);

  hipMemsetAsync(cnt, 0, NEXP * sizeof(int), stream);
  hipMemsetAsync(out, 0, (size_t)out_size * sizeof(float), stream);
  router_kernel<<<NTOK / 256, 256, 0, stream>>>(attr, Wr, br, scale, cnt, list);
  setup_kernel<<<1, 256, 0, stream>>>(cnt, list, rbexp, glist);
  gather_kernel<<<(NPAD * (DIM / 8)) / 256, 256, 0, stream>>>(x, glist, (uint4*)xg);

  // W1 [E][512][2048] -> W1t [E][2048][512]
  transpose_bf16_kernel<<<dim3(FDIM / 32, DIM / 32, NEXP), 256, 0, stream>>>(W1, WT, DIM, FDIM);
  // GEMM1: H = gelu(xg @ W1 + b1), K=512; flat grid 16*72, XCD-chunked
  moe_gemm_kernel<DIM, FDIM, FDIM / 128, true, 1>
      <<<(FDIM / 128) * NRB_MAX, 256, 0, stream>>>(
      xg, WT, b1, rbexp, glist, scale, H, nullptr);
  // W2 [E][2048][512] -> W2t [E][512][2048]  (reuses WT region)
  transpose_bf16_kernel<<<dim3(DIM / 32, FDIM / 32, NEXP), 256, 0, stream>>>(W2, WT, FDIM, DIM);
  // GEMM2: out = (H @ W2 + b2) * scale, K=2048 split 2 ways; flat 4*72*2, XCD-chunked
  moe_gemm_kernel<FDIM, DIM, DIM / 128, false, 2>
      <<<(DIM / 128) * NRB_MAX * 2, 256, 0, stream>>>(
      H, WT, b2, rbexp, glist, scale, nullptr, out);
}